// Round 1
// 5458.999 us; speedup vs baseline: 1.4427x; 1.4427x over previous
//
#include <hip/hip_runtime.h>
#include <cstdint>
#include <cstddef>

// Decoder (DA-RNN): B=512, T=256, E=D=256.
// Round 3: occupancy restructure. k_scan goes 512->1024 threads/block
// (16 waves/CU, was 8; grid 256 = 1 block/CU either way), with every phase
// re-split so per-thread work halves and per-wave dependency chains shorten.
// Weight reuse across the block's 2 batch rows stays in registers (splitting
// rows across blocks would double the L2 weight streams). 5 barriers/step.

typedef _Float16 half8 __attribute__((ext_vector_type(8)));
typedef _Float16 half4v __attribute__((ext_vector_type(4)));
typedef _Float16 half2v __attribute__((ext_vector_type(2)));

__device__ __forceinline__ float rcpf_(float x) { return __builtin_amdgcn_rcpf(x); }
__device__ __forceinline__ float sigmoidf_(float x) { return rcpf_(1.f + __expf(-x)); }
__device__ __forceinline__ float tanhf_(float x) { return 1.f - 2.f * rcpf_(1.f + __expf(2.f * x)); }

#if defined(__has_builtin)
#if __has_builtin(__builtin_amdgcn_fdot2)
#define HAS_FDOT2 1
#endif
#endif
#ifndef HAS_FDOT2
#define HAS_FDOT2 0
#endif

__device__ __forceinline__ float fdot2_(half2v a, half2v b, float c) {
#if HAS_FDOT2
  return __builtin_amdgcn_fdot2(a, b, c, false);
#else
  return fmaf((float)a[0], (float)b[0], fmaf((float)a[1], (float)b[1], c));
#endif
}

__device__ __forceinline__ float dot8_(half8 w, half8 h, float acc) {
  acc = fdot2_(__builtin_shufflevector(w, w, 0, 1), __builtin_shufflevector(h, h, 0, 1), acc);
  acc = fdot2_(__builtin_shufflevector(w, w, 2, 3), __builtin_shufflevector(h, h, 2, 3), acc);
  acc = fdot2_(__builtin_shufflevector(w, w, 4, 5), __builtin_shufflevector(h, h, 4, 5), acc);
  acc = fdot2_(__builtin_shufflevector(w, w, 6, 7), __builtin_shufflevector(h, h, 6, 7), acc);
  return acc;
}

// ---------------- prep kernels ----------------

// wT[e*256+f] = attn_w1[f*768 + 512 + e]   (transposed w1_enc, fp32)
__global__ void k_prep_wT(const float* __restrict__ w1, float* __restrict__ wT) {
  int id = blockIdx.x * 256 + threadIdx.x;
  int e = id >> 8, f = id & 255;
  wT[id] = w1[f * 768 + 512 + e];
}

// x -> fp16 (4 elems/thread), layout unchanged [b][t][e]
__global__ void k_prep_xh(const float* __restrict__ x, _Float16* __restrict__ xh) {
  int id = blockIdx.x * 256 + threadIdx.x;
  float4 v = reinterpret_cast<const float4*>(x)[id];
  half4v h;
  h[0] = (_Float16)v.x; h[1] = (_Float16)v.y; h[2] = (_Float16)v.z; h[3] = (_Float16)v.w;
  reinterpret_cast<half4v*>(xh)[id] = h;
}

// w1hcQ[(c*1024 + tid)*8 + m] = w1[e*768 + k], tid=(e<<2)|jk, k=jk*128+c*8+m, c in [0,16)
// (thread tid of k_scan's q phase reads chunk c as contiguous 16B, k-split 4)
__global__ void k_prep_w1hcQ(const float* __restrict__ w1, _Float16* __restrict__ o) {
  int id = blockIdx.x * 256 + threadIdx.x;  // 131072 total
  int m = id & 7, t = (id >> 3) & 1023, c = id >> 13;
  int e = t >> 2, jk = t & 3;
  int k = jk * 128 + c * 8 + m;
  o[id] = (_Float16)w1[e * 768 + k];
}

// whhG[(((jk*8 + c)*4 + jslot)*256 + jo)*8 + m] = Whh[(jslot*256+jo)*256 + jk*64 + c*8 + m]
// (thread (jo,jk) computes 4 outputs jslot*256+jo over k in [jk*64, jk*64+64))
__global__ void k_prep_whhG(const float* __restrict__ whh, _Float16* __restrict__ o) {
  int id = blockIdx.x * 256 + threadIdx.x;  // 262144 total
  int m = id & 7, jo = (id >> 3) & 255, jslot = (id >> 11) & 3;
  int c = (id >> 13) & 7, jk = (id >> 16) & 3;
  int j = jslot * 256 + jo, k = jk * 64 + c * 8 + m;
  o[id] = (_Float16)whh[j * 256 + k];
}

// xf[b*256+t] = sum_e x[b,t,e] * fcw[e]   (fp32)
__global__ __launch_bounds__(256) void k_xf(const float* __restrict__ x,
                                            const float* __restrict__ fcw,
                                            float* __restrict__ xf) {
  __shared__ float xl[16][256];
  __shared__ float fw[256];
  __shared__ float part[16][17];
  const int tid = threadIdx.x;
  const int m0 = blockIdx.x * 16;
  fw[tid] = fcw[tid];
#pragma unroll
  for (int r = 0; r < 16; ++r) xl[r][tid] = x[(size_t)(m0 + r) * 256 + tid];
  __syncthreads();
  int r = tid >> 4, p = tid & 15;
  float s = 0.f;
#pragma unroll
  for (int u = 0; u < 16; ++u) s = fmaf(xl[r][p * 16 + u], fw[p * 16 + u], s);
  part[r][p] = s;
  __syncthreads();
  if (tid < 16) {
    float t = 0.f;
#pragma unroll
    for (int p2 = 0; p2 < 16; ++p2) t += part[tid][p2];
    xf[m0 + tid] = t;
  }
}

// enc_proj GEMM + bias, store P=exp(2*encp) fp16 in layout [b][e/8][t][e%8]
__global__ __launch_bounds__(256) void k_encp(const float* __restrict__ x,
                                              const float* __restrict__ wT,
                                              const float* __restrict__ b1,
                                              _Float16* __restrict__ Ph2) {
  __shared__ __align__(16) float xl[16][256];
  const int tid = threadIdx.x;
  const int m0 = blockIdx.x * 16;
#pragma unroll
  for (int r = 0; r < 16; ++r) xl[r][tid] = x[(size_t)(m0 + r) * 256 + tid];
  __syncthreads();
  float acc[16];
#pragma unroll
  for (int r = 0; r < 16; ++r) acc[r] = 0.f;
  for (int e = 0; e < 256; e += 4) {
    float w0 = wT[(e + 0) * 256 + tid];
    float w1_ = wT[(e + 1) * 256 + tid];
    float w2_ = wT[(e + 2) * 256 + tid];
    float w3_ = wT[(e + 3) * 256 + tid];
#pragma unroll
    for (int r = 0; r < 16; ++r) {
      float4 xv = *reinterpret_cast<const float4*>(&xl[r][e]);
      acc[r] = fmaf(xv.x, w0, acc[r]);
      acc[r] = fmaf(xv.y, w1_, acc[r]);
      acc[r] = fmaf(xv.z, w2_, acc[r]);
      acc[r] = fmaf(xv.w, w3_, acc[r]);
    }
  }
  float bb = b1[tid];
  const int e = tid;
#pragma unroll
  for (int r = 0; r < 16; ++r) {
    int m = m0 + r, b = m >> 8, t = m & 255;
    float p = __expf(2.f * (acc[r] + bb));
    Ph2[((size_t)(b * 32 + (e >> 3)) * 256 + t) * 8 + (e & 7)] = (_Float16)p;
  }
}

// ---------------- the scan ----------------
// grid 256 x 1024 threads; wg owns 2 batch rows; 256 steps; 16 waves/CU.
__global__ __launch_bounds__(1024, 4) void k_scan(
    const _Float16* __restrict__ Ph2, const _Float16* __restrict__ xh,
    const _Float16* __restrict__ w1hcQ, const _Float16* __restrict__ whhG,
    const float* __restrict__ xf, const float* __restrict__ y_hist,
    const float* __restrict__ w2g, const float* __restrict__ Wih,
    const float* __restrict__ bih, const float* __restrict__ bhh,
    const float* __restrict__ fcw, const float* __restrict__ fcb,
    const float* __restrict__ fcfw, const float* __restrict__ fcfb,
    float* __restrict__ out) {
  __shared__ __align__(16) float hc[2][512];        // fp32 [g][ h | c ]
  __shared__ __align__(16) _Float16 hcH[2][512];    // fp16 mirror for dot2
  __shared__ __align__(16) float qpart[4][2][256];  // [jk][g][e]
  __shared__ __align__(16) float Qs[2][256];        // exp(2q)
  __shared__ __align__(16) float spart[2][2][256];  // [eh][g][t]
  __shared__ __align__(16) float ealpha[2][256];
  __shared__ __align__(16) float gpart[4][2][1024]; // [jk][g][j]; aliased post-loop as cpart[2][16][256]
  __shared__ __align__(16) float w2l[256];
  __shared__ __align__(16) float Wihl[1024];
  __shared__ __align__(16) float bl[1024];
  __shared__ __align__(16) float xfL[2][256];
  __shared__ __align__(16) float yhL[2][256];
  __shared__ float redA[8], redB[8];

  const int tid = threadIdx.x;
  const int b0 = blockIdx.x * 2;

  // ---- init ----
  ((float*)hc)[tid] = 0.f;
  ((_Float16*)hcH)[tid] = (_Float16)0.f;
  if (tid < 256) w2l[tid] = w2g[tid];
  Wihl[tid] = Wih[tid];
  bl[tid] = bih[tid] + bhh[tid];
  if (tid < 512) {
    int gi = tid >> 8, ti = tid & 255;
    xfL[gi][ti] = xf[(size_t)(b0 + gi) * 256 + ti];
    yhL[gi][ti] = y_hist[(size_t)(b0 + gi) * 256 + ti];
  }
  __syncthreads();
  float w2sum = 0.f;
  for (int e2 = 0; e2 < 256; ++e2) w2sum += w2l[e2];
  const float fcb0 = fcb[0];
  const float fcwy = fcw[256];

  // per-thread role constants
  // q phase: thread = (e = tid>>2, jk = tid&3), k in [jk*128, jk*128+128), both rows
  const int jkq = tid & 3, eQ = tid >> 2;
  const half8* wq = reinterpret_cast<const half8*>(w1hcQ) + tid;  // chunk c: wq[c*1024]
  const int hq0 = jkq * 128;
  // scores: thread = (g = tid>>9, eh = (tid>>8)&1, t = tid&255), e in [eh*128, eh*128+128)
  const int gs = tid >> 9, ts = tid & 255, eh = (tid >> 8) & 1;
  const half8* prow = reinterpret_cast<const half8*>(Ph2) +
                      ((size_t)((b0 + gs) * 32 + eh * 16)) * 256 + ts;
  // gates: thread = (jo = tid&255, jk = tid>>8); outputs jslot*256+jo, k in [jk*64, jk*64+64)
  const int jo = tid & 255, jkg = tid >> 8;
  const half8* wg = reinterpret_cast<const half8*>(whhG) + (size_t)jkg * 8192 + jo;
  const int hg0 = jkg * 64;
  // pointwise / softmax-combine (tid < 512)
  const int gp = (tid >> 8) & 1;
  const int tt = tid & 255;
  const int wv = tid >> 6, lane = tid & 63;

#pragma unroll 1
  for (int s = 0; s < 256; ++s) {
    // ---- phase 1: q[e] = hc . w1_hc[e,:], k-split 4, both rows ----
    float a0 = 0.f, a1 = 0.f;
    {
      const half8* h0p = reinterpret_cast<const half8*>(&hcH[0][hq0]);
      const half8* h1p = reinterpret_cast<const half8*>(&hcH[1][hq0]);
#pragma unroll 8
      for (int c = 0; c < 16; ++c) {
        half8 w = wq[c * 1024];
        half8 h0 = h0p[c];
        half8 h1 = h1p[c];
        a0 = dot8_(w, h0, a0);
        a1 = dot8_(w, h1, a1);
      }
    }
    qpart[jkq][0][eQ] = a0;
    qpart[jkq][1][eQ] = a1;
    __syncthreads();  // B1

    // ---- phase 2: Qs (half the threads) + gates GEMV h@Whh (all threads) ----
    if (tid < 512) {
      float qv = qpart[0][gp][tt] + qpart[1][gp][tt] + qpart[2][gp][tt] + qpart[3][gp][tt];
      Qs[gp][tt] = __expf(2.f * qv);
    }
    float ac0[4], ac1[4];
#pragma unroll
    for (int m = 0; m < 4; ++m) { ac0[m] = 0.f; ac1[m] = 0.f; }
    {
      const half8* hg0p = reinterpret_cast<const half8*>(&hcH[0][hg0]);
      const half8* hg1p = reinterpret_cast<const half8*>(&hcH[1][hg0]);
#pragma unroll 2
      for (int c = 0; c < 8; ++c) {
        half8 h0 = hg0p[c];
        half8 h1 = hg1p[c];
#pragma unroll
        for (int jslot = 0; jslot < 4; ++jslot) {
          half8 w = wg[(c * 4 + jslot) * 256];
          ac0[jslot] = dot8_(w, h0, ac0[jslot]);
          ac1[jslot] = dot8_(w, h1, ac1[jslot]);
        }
      }
    }
#pragma unroll
    for (int jslot = 0; jslot < 4; ++jslot) {
      gpart[jkg][0][jslot * 256 + jo] = ac0[jslot];
      gpart[jkg][1][jslot * 256 + jo] = ac1[jslot];
    }
    __syncthreads();  // B2

    // ---- phase 3: scores, e-split 2: sacc = sum_e w2[e]/(P*Q+1) ----
    float sacc0 = 0.f, sacc1 = 0.f;
    {
      const float4* q4 = reinterpret_cast<const float4*>(&Qs[gs][eh * 128]);
      const float4* w4 = reinterpret_cast<const float4*>(&w2l[eh * 128]);
#pragma unroll 8
      for (int c = 0; c < 16; ++c) {
        half8 pv = __builtin_nontemporal_load(prow + c * 256);
        float4 qa = q4[2 * c], qb = q4[2 * c + 1];
        float4 wa = w4[2 * c], wb = w4[2 * c + 1];
        sacc0 = fmaf(wa.x, rcpf_(fmaf((float)pv[0], qa.x, 1.f)), sacc0);
        sacc1 = fmaf(wa.y, rcpf_(fmaf((float)pv[1], qa.y, 1.f)), sacc1);
        sacc0 = fmaf(wa.z, rcpf_(fmaf((float)pv[2], qa.z, 1.f)), sacc0);
        sacc1 = fmaf(wa.w, rcpf_(fmaf((float)pv[3], qa.w, 1.f)), sacc1);
        sacc0 = fmaf(wb.x, rcpf_(fmaf((float)pv[4], qb.x, 1.f)), sacc0);
        sacc1 = fmaf(wb.y, rcpf_(fmaf((float)pv[5], qb.y, 1.f)), sacc1);
        sacc0 = fmaf(wb.z, rcpf_(fmaf((float)pv[6], qb.z, 1.f)), sacc0);
        sacc1 = fmaf(wb.w, rcpf_(fmaf((float)pv[7], qb.w, 1.f)), sacc1);
      }
    }
    spart[eh][gs][ts] = sacc0 + sacc1;
    __syncthreads();  // B3

    // ---- phase 4: combine + softmax reduce (tid < 512) ----
    if (tid < 512) {
      float sc = w2sum - 2.f * (spart[0][gp][tt] + spart[1][gp][tt]);
      float ea = __expf(sc);  // no max-sub: |sc| <= ~21, fp32-safe
      ealpha[gp][tt] = ea;
      float ef = ea * xfL[gp][tt];
      float es = ea;
#pragma unroll
      for (int off = 32; off > 0; off >>= 1) {
        es += __shfl_xor(es, off);
        ef += __shfl_xor(ef, off);
      }
      if (lane == 0) { redA[wv] = es; redB[wv] = ef; }
    }
    __syncthreads();  // B4

    // ---- phase 5: LSTM pointwise (tid < 512) ----
    if (tid < 512) {
      float es = (gp == 0) ? (redA[0] + redA[1] + redA[2] + redA[3])
                           : (redA[4] + redA[5] + redA[6] + redA[7]);
      float ef = (gp == 0) ? (redB[0] + redB[1] + redB[2] + redB[3])
                           : (redB[4] + redB[5] + redB[6] + redB[7]);
      float yt = ef * rcpf_(es) + fmaf(yhL[gp][s], fcwy, fcb0);
      float gi = fmaf(yt, Wihl[tt], bl[tt]);
      float gf = fmaf(yt, Wihl[256 + tt], bl[256 + tt]);
      float gc = fmaf(yt, Wihl[512 + tt], bl[512 + tt]);
      float go = fmaf(yt, Wihl[768 + tt], bl[768 + tt]);
#pragma unroll
      for (int q2 = 0; q2 < 4; ++q2) {
        gi += gpart[q2][gp][tt];
        gf += gpart[q2][gp][256 + tt];
        gc += gpart[q2][gp][512 + tt];
        go += gpart[q2][gp][768 + tt];
      }
      float iv = sigmoidf_(gi), fv = sigmoidf_(gf), gv = tanhf_(gc), ov = sigmoidf_(go);
      float cold = hc[gp][256 + tt];
      float cn = fmaf(fv, cold, iv * gv);
      float hn = ov * tanhf_(cn);
      hc[gp][tt] = hn;
      hc[gp][256 + tt] = cn;
      hcH[gp][tt] = (_Float16)hn;
      hcH[gp][256 + tt] = (_Float16)cn;
    }
    __syncthreads();  // B5
  }

  // ---- epilogue: context from step-255 ealpha, then out = [h|ctx].fcf ----
  // read last-step softmax sums BEFORE redA/redB get reused
  const float rsA = rcpf_(redA[0] + redA[1] + redA[2] + redA[3]);
  const float rsB = rcpf_(redA[4] + redA[5] + redA[6] + redA[7]);

  float* cpartF = &gpart[0][0][0];  // alias: cpart[g][u][t] = cpartF[(g*16+u)*256+t]
  {
    const int gc = tid >> 9, t16 = (tid >> 5) & 15, l5 = tid & 31;
    const half8* xrow = reinterpret_cast<const half8*>(xh) +
                        ((size_t)(b0 + gc) * 256 + t16 * 16) * 32 + l5;
    float acx[8];
#pragma unroll
    for (int m = 0; m < 8; ++m) acx[m] = 0.f;
#pragma unroll 4
    for (int it = 0; it < 16; ++it) {
      float al = ealpha[gc][t16 * 16 + it];
      half8 xv = xrow[it * 32];
#pragma unroll
      for (int m = 0; m < 8; ++m) acx[m] = fmaf(al, (float)xv[m], acx[m]);
    }
    float* dst = &cpartF[((gc * 16 + t16) * 256) + l5 * 8];
    *reinterpret_cast<float4*>(dst) = *reinterpret_cast<float4*>(&acx[0]);
    *reinterpret_cast<float4*>(dst + 4) = *reinterpret_cast<float4*>(&acx[4]);
  }
  __syncthreads();

  if (tid < 512) {
    float cv = 0.f;
#pragma unroll
    for (int u = 0; u < 16; ++u) cv += cpartF[((gp * 16 + u) * 256) + tt];
    cv *= (gp == 0) ? rsA : rsB;
    float hval = hc[gp][tt];
    float p0 = hval * fcfw[tt] + cv * fcfw[256 + tt];
    float p1 = hval * fcfw[512 + tt] + cv * fcfw[768 + tt];
#pragma unroll
    for (int off = 32; off > 0; off >>= 1) {
      p0 += __shfl_xor(p0, off);
      p1 += __shfl_xor(p1, off);
    }
    if (lane == 0) { redA[wv] = p0; redB[wv] = p1; }
  }
  __syncthreads();
  if (tid < 4) {
    int g2 = tid >> 1, o = tid & 1;
    const float* r = (o == 0) ? redA : redB;
    float v = fcfb[o] + r[g2 * 4 + 0] + r[g2 * 4 + 1] + r[g2 * 4 + 2] + r[g2 * 4 + 3];
    out[(b0 + g2) * 2 + o] = v;
  }
}

extern "C" void kernel_launch(void* const* d_in, const int* in_sizes, int n_in,
                              void* d_out, int out_size, void* d_ws, size_t ws_size,
                              hipStream_t stream) {
  (void)in_sizes; (void)n_in; (void)out_size; (void)ws_size;
  const float* x    = (const float*)d_in[0];
  const float* yh   = (const float*)d_in[1];
  const float* w1   = (const float*)d_in[2];
  const float* b1   = (const float*)d_in[3];
  const float* w2   = (const float*)d_in[4];
  /* d_in[5] attn_b2: softmax-invariant, unused */
  const float* Wih  = (const float*)d_in[6];
  const float* Whh  = (const float*)d_in[7];
  const float* bih  = (const float*)d_in[8];
  const float* bhh  = (const float*)d_in[9];
  const float* fcw  = (const float*)d_in[10];
  const float* fcb  = (const float*)d_in[11];
  const float* fcfw = (const float*)d_in[12];
  const float* fcfb = (const float*)d_in[13];
  float* out = (float*)d_out;

  char* ws = (char*)d_ws;
  _Float16* Ph2   = (_Float16*)(ws);                      // 67108864 B
  _Float16* xh    = (_Float16*)(ws + (size_t)67108864);   // 67108864 B
  float*    wT    = (float*)   (ws + (size_t)134217728);  // 262144 B
  _Float16* w1hcQ = (_Float16*)(ws + (size_t)134479872);  // 262144 B
  _Float16* whhG  = (_Float16*)(ws + (size_t)134742016);  // 524288 B
  float*    xf    = (float*)   (ws + (size_t)135266304);  // 524288 B
  // total: 135790592 B (~129.5 MB)

  k_prep_wT   <<<256,   256, 0, stream>>>(w1, wT);
  k_prep_xh   <<<32768, 256, 0, stream>>>(x, xh);
  k_prep_w1hcQ<<<512,   256, 0, stream>>>(w1, w1hcQ);
  k_prep_whhG <<<1024,  256, 0, stream>>>(Whh, whhG);
  k_xf        <<<8192,  256, 0, stream>>>(x, fcw, xf);
  k_encp      <<<8192,  256, 0, stream>>>(x, wT, b1, Ph2);
  k_scan      <<<256,  1024, 0, stream>>>(Ph2, xh, w1hcQ, whhG, xf, yh, w2, Wih,
                                          bih, bhh, fcw, fcb, fcfw, fcfb, out);
}